// Round 1
// baseline (726.645 us; speedup 1.0000x reference)
//
#include <hip/hip_runtime.h>

#define BB 2
#define S 2048
#define H 16
#define DH 64
#define DIM 1024
#define WIN 512

#define OUT_PK 0
#define OUT_QP 134217728
#define OUT_RQ 268435456
#define OUT_RK 268959744

// ws float offsets (total ~1.03 MB)
#define WS_MU    0
#define WS_RSTD  512
#define WS_C0Q   1024
#define WS_C511Q (1024 + 65536)
#define WS_C0K   (1024 + 2*65536)
#define WS_C511K (1024 + 3*65536)

__global__ void ln_stats(const float* __restrict__ emb, float* __restrict__ ws) {
    int row = blockIdx.x;
    int t = threadIdx.x; // 64 threads
    const float4* rp = reinterpret_cast<const float4*>(emb + row * DIM);
    float s = 0.f, sq = 0.f;
#pragma unroll
    for (int i = 0; i < 4; ++i) {
        float4 v = rp[t + 64 * i];
        s  += v.x + v.y + v.z + v.w;
        sq += v.x * v.x + v.y * v.y + v.z * v.z + v.w * v.w;
    }
    for (int m = 32; m; m >>= 1) { s += __shfl_xor(s, m); sq += __shfl_xor(sq, m); }
    if (t == 0) {
        float mu = s / DIM;
        float var = sq / DIM - mu * mu;
        ws[WS_MU + row] = mu;
        ws[WS_RSTD + row] = rsqrtf(var + 1e-5f);
    }
}

// C[r,d] = sum_c LN(emb)[r,c] * W[d,c] + bias[d];  z=0 -> Wq -> OUT_RQ, z=1 -> Wk -> OUT_RK
__global__ __launch_bounds__(256) void proj(const float* __restrict__ emb,
        const float* __restrict__ ws, const float* __restrict__ lnsc, const float* __restrict__ lnbi,
        const float* __restrict__ Wq, const float* __restrict__ bq,
        const float* __restrict__ Wk, const float* __restrict__ bk,
        float* __restrict__ out) {
    const float* W    = blockIdx.z ? Wk : Wq;
    const float* bias = blockIdx.z ? bk : bq;
    float* o = out + (blockIdx.z ? OUT_RK : OUT_RQ);
    int r0 = blockIdx.x * 64;   // gridDim.x = 8
    int d0 = blockIdx.y * 64;   // gridDim.y = 16
    __shared__ float As[32 * 65];
    __shared__ float Bs[32 * 65];
    int t = threadIdx.x;
    int tx = t & 15, ty = t >> 4;
    float muv[8], rsv[8];
#pragma unroll
    for (int i = 0; i < 8; ++i) {
        int r = (t + i * 256) >> 5;
        muv[i] = ws[WS_MU + r0 + r];
        rsv[i] = ws[WS_RSTD + r0 + r];
    }
    float acc[4][4] = {};
    for (int c0 = 0; c0 < DIM; c0 += 32) {
#pragma unroll
        for (int i = 0; i < 8; ++i) {
            int idx = t + i * 256;
            int r = idx >> 5, c = idx & 31;
            float raw = emb[(r0 + r) * DIM + c0 + c];
            float v = (raw - muv[i]) * rsv[i] * lnsc[c0 + c] + lnbi[c0 + c];
            As[c * 65 + r] = v;
            Bs[c * 65 + r] = W[(d0 + r) * DIM + c0 + c];
        }
        __syncthreads();
#pragma unroll
        for (int c = 0; c < 32; ++c) {
            float a[4], b[4];
#pragma unroll
            for (int i = 0; i < 4; ++i) a[i] = As[c * 65 + ty * 4 + i];
#pragma unroll
            for (int j = 0; j < 4; ++j) b[j] = Bs[c * 65 + tx * 4 + j];
#pragma unroll
            for (int i = 0; i < 4; ++i)
#pragma unroll
                for (int j = 0; j < 4; ++j) acc[i][j] += a[i] * b[j];
        }
        __syncthreads();
    }
#pragma unroll
    for (int i = 0; i < 4; ++i) {
        int row = r0 + ty * 4 + i, col = d0 + tx * 4;
        float4 v = { acc[i][0] + bias[col], acc[i][1] + bias[col + 1],
                     acc[i][2] + bias[col + 2], acc[i][3] + bias[col + 3] };
        *reinterpret_cast<float4*>(o + row * DIM + col) = v;
    }
}

// QSIDE=1: c0q/c511q[n] = q[b,n,h]·rk[0/511,h];  QSIDE=0: c0k/c511k[j] = k[b,j,h]·rq[0/511,h]
template<int QSIDE>
__global__ __launch_bounds__(256) void cvec(const float* __restrict__ X,
        const float* __restrict__ dout_ro, float* __restrict__ ws) {
    int bh = blockIdx.y; int b = bh >> 4, h = bh & 15;
    int row = blockIdx.x * 64 + (threadIdx.x >> 2);
    int seg = (threadIdx.x & 3) * 16;
    const float* T = dout_ro + (QSIDE ? OUT_RK : OUT_RQ);
    const float4* xp = reinterpret_cast<const float4*>(X + (size_t)((b * S + row) * H + h) * DH + seg);
    const float4* t0 = reinterpret_cast<const float4*>(T + h * DH + seg);
    const float4* t1 = reinterpret_cast<const float4*>(T + 511 * DIM + h * DH + seg);
    float d0 = 0.f, d1 = 0.f;
#pragma unroll
    for (int i = 0; i < 4; ++i) {
        float4 x = xp[i], a = t0[i], c = t1[i];
        d0 += x.x * a.x + x.y * a.y + x.z * a.z + x.w * a.w;
        d1 += x.x * c.x + x.y * c.y + x.z * c.z + x.w * c.w;
    }
    d0 += __shfl_xor(d0, 1); d0 += __shfl_xor(d0, 2);
    d1 += __shfl_xor(d1, 1); d1 += __shfl_xor(d1, 2);
    if ((threadIdx.x & 3) == 0) {
        int o = bh * S + row;
        if (QSIDE) { ws[WS_C0Q + o] = d0; ws[WS_C511Q + o] = d1; }
        else       { ws[WS_C0K + o] = d0; ws[WS_C511K + o] = d1; }
    }
}

// Flat regions: j < jL and j >= jR for n-tile [n0, n0+64)
template<int PK>
__global__ __launch_bounds__(256) void flatfill(const float* __restrict__ ws, float* __restrict__ out) {
    int bh = blockIdx.y;
    int n0 = blockIdx.x * 64;
    int m = n0 >> 6;
    int jt_lo = m > 8 ? m - 8 : 0;
    int jt_hi = m + 1;
    int jL = jt_lo * 64, jR = jt_hi * 64;
    int t = threadIdx.x;
    float* obase = out + (PK ? OUT_PK : OUT_QP) + (size_t)bh * S * S;
    const float* c0 = ws + (PK ? WS_C0K : WS_C0Q) + bh * S;
    const float* c1 = ws + (PK ? WS_C511K : WS_C511Q) + bh * S;
    for (int i = 0; i < 64; ++i) {
        int n = n0 + i;
        float* orow = obase + (size_t)n * S;
        if (PK) {
            for (int j4 = t; j4 < (jL >> 2); j4 += 256)
                reinterpret_cast<float4*>(orow)[j4] = reinterpret_cast<const float4*>(c0)[j4];
            int nr = (S - jR) >> 2;
            const float4* c1v = reinterpret_cast<const float4*>(c1 + jR);
            float4* ov = reinterpret_cast<float4*>(orow + jR);
            for (int j4 = t; j4 < nr; j4 += 256) ov[j4] = c1v[j4];
        } else {
            float v0 = c0[n], v1 = c1[n];
            float4 f0 = {v0, v0, v0, v0}, f1 = {v1, v1, v1, v1};
            for (int j4 = t; j4 < (jL >> 2); j4 += 256)
                reinterpret_cast<float4*>(orow)[j4] = f0;
            int nr = (S - jR) >> 2;
            float4* ov = reinterpret_cast<float4*>(orow + jR);
            for (int j4 = t; j4 < nr; j4 += 256) ov[j4] = f1;
        }
    }
}

// Band tiles: 64x64 outputs, clamped-rel dot-64.
// PK=1: out_pk[n,j] = k[b,j,h]·rq[rel,h]; PK=0: out_qp[n,j] = q[b,n,h]·rk[rel,h]
template<int PK>
__global__ __launch_bounds__(256) void band(const float* __restrict__ X,
        const float* __restrict__ dout_ro, float* __restrict__ out) {
    int bh = blockIdx.y; int b = bh >> 4, h = bh & 15;
    int nt = blockIdx.x / 9, sub = blockIdx.x % 9;
    int n0 = nt * 64;
    int jt_lo = nt > 8 ? nt - 8 : 0;
    int jt_hi = nt + 1;
    int jt = jt_lo + sub;
    if (jt >= jt_hi) return;
    int j0 = jt * 64;
    int rlo = 511 + j0 - (n0 + 63); rlo = rlo < 0 ? 0 : (rlo > 511 ? 511 : rlo);
    int rhi = 511 + (j0 + 63) - n0; rhi = rhi < 0 ? 0 : (rhi > 511 ? 511 : rhi);
    int nT = rhi - rlo + 1;
    __shared__ float Xs[64 * 65];
    __shared__ float Ts[128 * 65];
    const float* T = dout_ro + (PK ? OUT_RQ : OUT_RK);
    int t = threadIdx.x;
    int xbase_row = PK ? j0 : n0;
#pragma unroll
    for (int i = 0; i < 4; ++i) {
        int idx = t + i * 256;                       // 1024 float4s
        int row = idx >> 4, c4 = idx & 15;
        float4 v = *reinterpret_cast<const float4*>(X + (size_t)((b * S + xbase_row + row) * H + h) * DH + c4 * 4);
        float* dst = &Xs[row * 65 + c4 * 4];
        dst[0] = v.x; dst[1] = v.y; dst[2] = v.z; dst[3] = v.w;
    }
    for (int idx = t; idx < nT * 16; idx += 256) {
        int row = idx >> 4, c4 = idx & 15;
        float4 v = *reinterpret_cast<const float4*>(T + (size_t)(rlo + row) * DIM + h * DH + c4 * 4);
        float* dst = &Ts[row * 65 + c4 * 4];
        dst[0] = v.x; dst[1] = v.y; dst[2] = v.z; dst[3] = v.w;
    }
    __syncthreads();
    int tx = t & 15, ty = t >> 4;
    int R0 = 511 + (j0 + tx * 4) - (n0 + ty * 4);   // rel at (i=0, jj=0)
    int trow[7];
#pragma unroll
    for (int d = 0; d < 7; ++d) {
        int rel = R0 + d - 3;
        rel = rel < 0 ? 0 : (rel > 511 ? 511 : rel);
        trow[d] = rel - rlo;
    }
    float acc[4][4] = {};
    for (int c = 0; c < 64; ++c) {
        float tv[7];
#pragma unroll
        for (int d = 0; d < 7; ++d) tv[d] = Ts[trow[d] * 65 + c];
        float xv[4];
#pragma unroll
        for (int u = 0; u < 4; ++u) xv[u] = Xs[((PK ? tx : ty) * 4 + u) * 65 + c];
#pragma unroll
        for (int i = 0; i < 4; ++i)
#pragma unroll
            for (int jj = 0; jj < 4; ++jj)
                acc[i][jj] += (PK ? xv[jj] : xv[i]) * tv[jj - i + 3];
    }
    float* obase = out + (PK ? OUT_PK : OUT_QP) + (size_t)bh * S * S;
#pragma unroll
    for (int i = 0; i < 4; ++i) {
        int n = n0 + ty * 4 + i;
        float4 v = { acc[i][0], acc[i][1], acc[i][2], acc[i][3] };
        *reinterpret_cast<float4*>(obase + (size_t)n * S + j0 + tx * 4) = v;
    }
}

extern "C" void kernel_launch(void* const* d_in, const int* in_sizes, int n_in,
                              void* d_out, int out_size, void* d_ws, size_t ws_size,
                              hipStream_t stream) {
    const float* q    = (const float*)d_in[0];
    const float* k    = (const float*)d_in[1];
    const float* emb  = (const float*)d_in[2];
    const float* lnsc = (const float*)d_in[3];
    const float* lnbi = (const float*)d_in[4];
    const float* Wq   = (const float*)d_in[5];
    const float* bq   = (const float*)d_in[6];
    const float* Wk   = (const float*)d_in[7];
    const float* bk   = (const float*)d_in[8];
    float* out = (float*)d_out;
    float* ws  = (float*)d_ws;

    ln_stats<<<dim3(512), dim3(64), 0, stream>>>(emb, ws);
    proj<<<dim3(8, 16, 2), dim3(256), 0, stream>>>(emb, ws, lnsc, lnbi, Wq, bq, Wk, bk, out);
    cvec<1><<<dim3(32, 32), dim3(256), 0, stream>>>(q, out, ws);
    cvec<0><<<dim3(32, 32), dim3(256), 0, stream>>>(k, out, ws);
    flatfill<1><<<dim3(32, 32), dim3(256), 0, stream>>>(ws, out);
    flatfill<0><<<dim3(32, 32), dim3(256), 0, stream>>>(ws, out);
    band<0><<<dim3(288, 32), dim3(256), 0, stream>>>(q, out, out);
    band<1><<<dim3(288, 32), dim3(256), 0, stream>>>(k, out, out);
}

// Round 2
// 458.926 us; speedup vs baseline: 1.5834x; 1.5834x over previous
//
#include <hip/hip_runtime.h>

#define BB 2
#define S 2048
#define H 16
#define DH 64
#define DIM 1024
#define WIN 512

#define OUT_PK 0
#define OUT_QP 134217728
#define OUT_RQ 268435456
#define OUT_RK 268959744

// ws float offsets
#define WS_MU    0
#define WS_RSTD  512
#define WS_C0Q   1024
#define WS_C511Q (1024 + 65536)
#define WS_C0K   (1024 + 2*65536)
#define WS_C511K (1024 + 3*65536)
#define WS_BF_BASE 263168          // float index where bf16 region starts

typedef short bf16x8 __attribute__((ext_vector_type(8)));
typedef float f32x4 __attribute__((ext_vector_type(4)));

__device__ inline short f2bf(float f) {
    union { float f; unsigned int u; } cv; cv.f = f;
    unsigned int u = cv.u + 0x7FFFu + ((cv.u >> 16) & 1u);
    return (short)(u >> 16);
}

__global__ void ln_stats(const float* __restrict__ emb, float* __restrict__ ws) {
    int row = blockIdx.x;
    int t = threadIdx.x; // 64 threads
    const float4* rp = reinterpret_cast<const float4*>(emb + row * DIM);
    float s = 0.f, sq = 0.f;
#pragma unroll
    for (int i = 0; i < 4; ++i) {
        float4 v = rp[t + 64 * i];
        s  += v.x + v.y + v.z + v.w;
        sq += v.x * v.x + v.y * v.y + v.z * v.z + v.w * v.w;
    }
    for (int m = 32; m; m >>= 1) { s += __shfl_xor(s, m); sq += __shfl_xor(sq, m); }
    if (t == 0) {
        float mu = s / DIM;
        float var = sq / DIM - mu * mu;
        ws[WS_MU + row] = mu;
        ws[WS_RSTD + row] = rsqrtf(var + 1e-5f);
    }
}

// C[r,d] = sum_c LN(emb)[r,c] * W[d,c] + bias[d];  z=0 -> Wq -> OUT_RQ, z=1 -> Wk -> OUT_RK
__global__ __launch_bounds__(256) void proj(const float* __restrict__ emb,
        const float* __restrict__ ws, const float* __restrict__ lnsc, const float* __restrict__ lnbi,
        const float* __restrict__ Wq, const float* __restrict__ bq,
        const float* __restrict__ Wk, const float* __restrict__ bk,
        float* __restrict__ out) {
    const float* W    = blockIdx.z ? Wk : Wq;
    const float* bias = blockIdx.z ? bk : bq;
    float* o = out + (blockIdx.z ? OUT_RK : OUT_RQ);
    int r0 = blockIdx.x * 64;   // gridDim.x = 8
    int d0 = blockIdx.y * 64;   // gridDim.y = 16
    __shared__ float As[32 * 65];
    __shared__ float Bs[32 * 65];
    int t = threadIdx.x;
    int tx = t & 15, ty = t >> 4;
    float muv[8], rsv[8];
#pragma unroll
    for (int i = 0; i < 8; ++i) {
        int r = (t + i * 256) >> 5;
        muv[i] = ws[WS_MU + r0 + r];
        rsv[i] = ws[WS_RSTD + r0 + r];
    }
    float acc[4][4] = {};
    for (int c0 = 0; c0 < DIM; c0 += 32) {
#pragma unroll
        for (int i = 0; i < 8; ++i) {
            int idx = t + i * 256;
            int r = idx >> 5, c = idx & 31;
            float raw = emb[(r0 + r) * DIM + c0 + c];
            float v = (raw - muv[i]) * rsv[i] * lnsc[c0 + c] + lnbi[c0 + c];
            As[c * 65 + r] = v;
            Bs[c * 65 + r] = W[(d0 + r) * DIM + c0 + c];
        }
        __syncthreads();
#pragma unroll
        for (int c = 0; c < 32; ++c) {
            float a[4], b[4];
#pragma unroll
            for (int i = 0; i < 4; ++i) a[i] = As[c * 65 + ty * 4 + i];
#pragma unroll
            for (int j = 0; j < 4; ++j) b[j] = Bs[c * 65 + tx * 4 + j];
#pragma unroll
            for (int i = 0; i < 4; ++i)
#pragma unroll
                for (int j = 0; j < 4; ++j) acc[i][j] += a[i] * b[j];
        }
        __syncthreads();
    }
#pragma unroll
    for (int i = 0; i < 4; ++i) {
        int row = r0 + ty * 4 + i, col = d0 + tx * 4;
        float4 v = { acc[i][0] + bias[col], acc[i][1] + bias[col + 1],
                     acc[i][2] + bias[col + 2], acc[i][3] + bias[col + 3] };
        *reinterpret_cast<float4*>(o + row * DIM + col) = v;
    }
}

// q,k f32 [b,n,h,c] -> bf16 [b,h,n,c]
__global__ __launch_bounds__(256) void tobf16_qk(const float* __restrict__ q,
        const float* __restrict__ k, short* __restrict__ qbf, short* __restrict__ kbf) {
    const float* src = blockIdx.y ? k : q;
    short* dst = blockIdx.y ? kbf : qbf;
    int idx = blockIdx.x * 256 + threadIdx.x;   // grid.x = 4096
    int e0 = idx * 4;
    int c = e0 & 63, hh = (e0 >> 6) & 15, n = (e0 >> 10) & 2047, b = e0 >> 21;
    float4 v = *reinterpret_cast<const float4*>(src + e0);
    short4 o = { f2bf(v.x), f2bf(v.y), f2bf(v.z), f2bf(v.w) };
    *reinterpret_cast<short4*>(dst + (((size_t)(b * 16 + hh) * 2048) + n) * 64 + c) = o;
}

// rq/rk f32 [r, h*64+c] (in out) -> bf16 [h, r, c]
__global__ __launch_bounds__(256) void tobf16_r(const float* __restrict__ out_ro,
        short* __restrict__ rqbf, short* __restrict__ rkbf) {
    const float* src = out_ro + (blockIdx.y ? OUT_RK : OUT_RQ);
    short* dst = blockIdx.y ? rkbf : rqbf;
    int idx = blockIdx.x * 256 + threadIdx.x;   // grid.x = 512
    int e0 = idx * 4;
    int r = e0 >> 10, rem = e0 & 1023, hh = rem >> 6, c = rem & 63;
    float4 v = *reinterpret_cast<const float4*>(src + e0);
    short4 o = { f2bf(v.x), f2bf(v.y), f2bf(v.z), f2bf(v.w) };
    *reinterpret_cast<short4*>(dst + ((size_t)(hh * 512 + r)) * 64 + c) = o;
}

// QSIDE=1: c0q/c511q[n] = q[b,n,h]·rk[0/511,h];  QSIDE=0: c0k/c511k[j] = k[b,j,h]·rq[0/511,h]
template<int QSIDE>
__global__ __launch_bounds__(256) void cvec(const float* __restrict__ X,
        const float* __restrict__ dout_ro, float* __restrict__ ws) {
    int bh = blockIdx.y; int b = bh >> 4, h = bh & 15;
    int row = blockIdx.x * 64 + (threadIdx.x >> 2);
    int seg = (threadIdx.x & 3) * 16;
    const float* T = dout_ro + (QSIDE ? OUT_RK : OUT_RQ);
    const float4* xp = reinterpret_cast<const float4*>(X + (size_t)((b * S + row) * H + h) * DH + seg);
    const float4* t0 = reinterpret_cast<const float4*>(T + h * DH + seg);
    const float4* t1 = reinterpret_cast<const float4*>(T + 511 * DIM + h * DH + seg);
    float d0 = 0.f, d1 = 0.f;
#pragma unroll
    for (int i = 0; i < 4; ++i) {
        float4 x = xp[i], a = t0[i], c = t1[i];
        d0 += x.x * a.x + x.y * a.y + x.z * a.z + x.w * a.w;
        d1 += x.x * c.x + x.y * c.y + x.z * c.z + x.w * c.w;
    }
    d0 += __shfl_xor(d0, 1); d0 += __shfl_xor(d0, 2);
    d1 += __shfl_xor(d1, 1); d1 += __shfl_xor(d1, 2);
    if ((threadIdx.x & 3) == 0) {
        int o = bh * S + row;
        if (QSIDE) { ws[WS_C0Q + o] = d0; ws[WS_C511Q + o] = d1; }
        else       { ws[WS_C0K + o] = d0; ws[WS_C511K + o] = d1; }
    }
}

// Flat regions: j < jL and j >= jR for n-tile [n0, n0+64)
template<int PK>
__global__ __launch_bounds__(256) void flatfill(const float* __restrict__ ws, float* __restrict__ out) {
    int bh = blockIdx.y;
    int n0 = blockIdx.x * 64;
    int m = n0 >> 6;
    int jt_lo = m > 8 ? m - 8 : 0;
    int jt_hi = m + 1;
    int jL = jt_lo * 64, jR = jt_hi * 64;
    int t = threadIdx.x;
    float* obase = out + (PK ? OUT_PK : OUT_QP) + (size_t)bh * S * S;
    const float* c0 = ws + (PK ? WS_C0K : WS_C0Q) + bh * S;
    const float* c1 = ws + (PK ? WS_C511K : WS_C511Q) + bh * S;
    for (int i = 0; i < 64; ++i) {
        int n = n0 + i;
        float* orow = obase + (size_t)n * S;
        if (PK) {
            for (int j4 = t; j4 < (jL >> 2); j4 += 256)
                reinterpret_cast<float4*>(orow)[j4] = reinterpret_cast<const float4*>(c0)[j4];
            int nr = (S - jR) >> 2;
            const float4* c1v = reinterpret_cast<const float4*>(c1 + jR);
            float4* ov = reinterpret_cast<float4*>(orow + jR);
            for (int j4 = t; j4 < nr; j4 += 256) ov[j4] = c1v[j4];
        } else {
            float v0 = c0[n], v1 = c1[n];
            float4 f0 = {v0, v0, v0, v0}, f1 = {v1, v1, v1, v1};
            for (int j4 = t; j4 < (jL >> 2); j4 += 256)
                reinterpret_cast<float4*>(orow)[j4] = f0;
            int nr = (S - jR) >> 2;
            float4* ov = reinterpret_cast<float4*>(orow + jR);
            for (int j4 = t; j4 < nr; j4 += 256) ov[j4] = f1;
        }
    }
}

// MFMA band tile: compute Y[m, r] = X[m] . T[rlo+r] (bf16 MFMA), then gather-store.
// PK=0 (qp): X = q rows n0..n0+63, T = rk;  out_qp[n,j] = Y[n-n0, rel-rlo]
// PK=1 (pk): X = k rows j0..j0+63, T = rq;  out_pk[n,j] = Y[j-j0, rel-rlo]
template<int PK>
__global__ __launch_bounds__(256) void bandm(const short* __restrict__ xbf,
        const short* __restrict__ tbf, float* __restrict__ out) {
    int bh = blockIdx.y; int h = bh & 15;
    int nt = blockIdx.x / 9, sub = blockIdx.x % 9;
    int jt_lo = nt > 8 ? nt - 8 : 0;
    int jt = jt_lo + sub;
    if (jt > nt) return;
    int n0 = nt * 64, j0 = jt * 64;
    int rlo = 511 + j0 - (n0 + 63); rlo = rlo < 0 ? 0 : rlo;
    int rhi = 511 + (j0 + 63) - n0; rhi = rhi > 511 ? 511 : rhi;
    int nT = rhi - rlo + 1;   // <= 127

    __shared__ short Xs[64 * 72];    // row stride 72 bf16 = 144 B
    __shared__ short Ts[128 * 72];
    __shared__ float Yt[128 * 68];   // transposed Y: Yt[r][m], stride 68 (16B-aligned)

    int t = threadIdx.x;
    const short* xb = xbf + ((size_t)bh * 2048 + (PK ? j0 : n0)) * 64;
    const short* tb = tbf + ((size_t)h * 512 + rlo) * 64;
#pragma unroll
    for (int i = 0; i < 2; ++i) {
        int idx = t + i * 256, row = idx >> 3, seg = idx & 7;
        *reinterpret_cast<uint4*>(&Xs[row * 72 + seg * 8]) =
            *reinterpret_cast<const uint4*>(xb + row * 64 + seg * 8);
    }
#pragma unroll
    for (int i = 0; i < 4; ++i) {
        int idx = t + i * 256, row = idx >> 3, seg = idx & 7;
        if (row < nT)
            *reinterpret_cast<uint4*>(&Ts[row * 72 + seg * 8]) =
                *reinterpret_cast<const uint4*>(tb + row * 64 + seg * 8);
    }
    __syncthreads();

    int lane = t & 63, wave = t >> 6;
    int lr = lane & 15, lg = lane >> 4;
    // A fragments: rows wave*16+lr of Xs, contiguous 8 bf16 per k-step.
    // Identical lane->(row,k-chunk) convention for A and B => any HW k-permutation cancels.
    bf16x8 a0 = *reinterpret_cast<const bf16x8*>(&Xs[(wave * 16 + lr) * 72 + lg * 8]);
    bf16x8 a1 = *reinterpret_cast<const bf16x8*>(&Xs[(wave * 16 + lr) * 72 + 32 + lg * 8]);
#pragma unroll
    for (int s = 0; s < 8; ++s) {
        bf16x8 b0 = *reinterpret_cast<const bf16x8*>(&Ts[(s * 16 + lr) * 72 + lg * 8]);
        bf16x8 b1 = *reinterpret_cast<const bf16x8*>(&Ts[(s * 16 + lr) * 72 + 32 + lg * 8]);
        f32x4 acc = {0.f, 0.f, 0.f, 0.f};
        acc = __builtin_amdgcn_mfma_f32_16x16x32_bf16(a0, b0, acc, 0, 0, 0);
        acc = __builtin_amdgcn_mfma_f32_16x16x32_bf16(a1, b1, acc, 0, 0, 0);
        // D layout: col(r_T)=lane&15, row(m)=(lane>>4)*4+reg  -> store transposed, b128
        *reinterpret_cast<f32x4*>(&Yt[(s * 16 + lr) * 68 + wave * 16 + lg * 4]) = acc;
    }
    __syncthreads();

    int tx = t & 15, ty = t >> 4;
    float* obase = out + (PK ? OUT_PK : OUT_QP) + (size_t)bh * S * S;
#pragma unroll
    for (int i = 0; i < 4; ++i) {
        int rowi = ty + i * 16;
        int n = n0 + rowi;
        float vv[4];
#pragma unroll
        for (int jj = 0; jj < 4; ++jj) {
            int j = j0 + tx * 4 + jj;
            int rel = 511 + j - n;
            rel = rel < 0 ? 0 : (rel > 511 ? 511 : rel);
            int g = rel - rlo;
            int m = PK ? (tx * 4 + jj) : rowi;
            vv[jj] = Yt[g * 68 + m];
        }
        float4 v = { vv[0], vv[1], vv[2], vv[3] };
        *reinterpret_cast<float4*>(obase + (size_t)n * S + j0 + tx * 4) = v;
    }
}

extern "C" void kernel_launch(void* const* d_in, const int* in_sizes, int n_in,
                              void* d_out, int out_size, void* d_ws, size_t ws_size,
                              hipStream_t stream) {
    const float* q    = (const float*)d_in[0];
    const float* k    = (const float*)d_in[1];
    const float* emb  = (const float*)d_in[2];
    const float* lnsc = (const float*)d_in[3];
    const float* lnbi = (const float*)d_in[4];
    const float* Wq   = (const float*)d_in[5];
    const float* bq   = (const float*)d_in[6];
    const float* Wk   = (const float*)d_in[7];
    const float* bk   = (const float*)d_in[8];
    float* out = (float*)d_out;
    float* ws  = (float*)d_ws;

    short* qbf  = (short*)(ws + WS_BF_BASE);
    short* kbf  = qbf + (size_t)4194304;
    short* rqbf = kbf + (size_t)4194304;
    short* rkbf = rqbf + (size_t)524288;

    ln_stats<<<dim3(512), dim3(64), 0, stream>>>(emb, ws);
    proj<<<dim3(8, 16, 2), dim3(256), 0, stream>>>(emb, ws, lnsc, lnbi, Wq, bq, Wk, bk, out);
    tobf16_qk<<<dim3(4096, 2), dim3(256), 0, stream>>>(q, k, qbf, kbf);
    tobf16_r<<<dim3(512, 2), dim3(256), 0, stream>>>(out, rqbf, rkbf);
    cvec<1><<<dim3(32, 32), dim3(256), 0, stream>>>(q, out, ws);
    cvec<0><<<dim3(32, 32), dim3(256), 0, stream>>>(k, out, ws);
    flatfill<1><<<dim3(32, 32), dim3(256), 0, stream>>>(ws, out);
    flatfill<0><<<dim3(32, 32), dim3(256), 0, stream>>>(ws, out);
    bandm<0><<<dim3(288, 32), dim3(256), 0, stream>>>(qbf, rkbf, out);
    bandm<1><<<dim3(288, 32), dim3(256), 0, stream>>>(kbf, rqbf, out);
}

// Round 3
// 410.265 us; speedup vs baseline: 1.7712x; 1.1186x over previous
//
#include <hip/hip_runtime.h>

#define BB 2
#define S 2048
#define H 16
#define DH 64
#define DIM 1024
#define WIN 512

#define OUT_PK 0
#define OUT_QP 134217728
#define OUT_RQ 268435456
#define OUT_RK 268959744

// ws float offsets
#define WS_MU    0
#define WS_RSTD  512
#define WS_C0Q   1024
#define WS_C511Q (1024 + 65536)
#define WS_C0K   (1024 + 2*65536)
#define WS_C511K (1024 + 3*65536)
#define WS_BF_BASE 263168          // float index where bf16 region starts

typedef short bf16x8 __attribute__((ext_vector_type(8)));
typedef float f32x4 __attribute__((ext_vector_type(4)));

__device__ inline short f2bf(float f) {
    union { float f; unsigned int u; } cv; cv.f = f;
    unsigned int u = cv.u + 0x7FFFu + ((cv.u >> 16) & 1u);
    return (short)(u >> 16);
}

__global__ void ln_stats(const float* __restrict__ emb, float* __restrict__ ws) {
    int row = blockIdx.x;
    int t = threadIdx.x; // 64 threads
    const float4* rp = reinterpret_cast<const float4*>(emb + row * DIM);
    float s = 0.f, sq = 0.f;
#pragma unroll
    for (int i = 0; i < 4; ++i) {
        float4 v = rp[t + 64 * i];
        s  += v.x + v.y + v.z + v.w;
        sq += v.x * v.x + v.y * v.y + v.z * v.z + v.w * v.w;
    }
    for (int m = 32; m; m >>= 1) { s += __shfl_xor(s, m); sq += __shfl_xor(sq, m); }
    if (t == 0) {
        float mu = s / DIM;
        float var = sq / DIM - mu * mu;
        ws[WS_MU + row] = mu;
        ws[WS_RSTD + row] = rsqrtf(var + 1e-5f);
    }
}

// C[r,d] = sum_c LN(emb)[r,c] * W[d,c] + bias[d];  z=0 -> Wq -> OUT_RQ (+rqbf), z=1 -> Wk -> OUT_RK (+rkbf)
__global__ __launch_bounds__(256) void proj(const float* __restrict__ emb,
        const float* __restrict__ ws, const float* __restrict__ lnsc, const float* __restrict__ lnbi,
        const float* __restrict__ Wq, const float* __restrict__ bq,
        const float* __restrict__ Wk, const float* __restrict__ bk,
        float* __restrict__ out, short* __restrict__ rqbf, short* __restrict__ rkbf) {
    const float* W    = blockIdx.z ? Wk : Wq;
    const float* bias = blockIdx.z ? bk : bq;
    float* o = out + (blockIdx.z ? OUT_RK : OUT_RQ);
    short* bfo = blockIdx.z ? rkbf : rqbf;
    int r0 = blockIdx.x * 64;   // gridDim.x = 8
    int d0 = blockIdx.y * 64;   // gridDim.y = 16
    __shared__ float As[32 * 65];
    __shared__ float Bs[32 * 65];
    int t = threadIdx.x;
    int tx = t & 15, ty = t >> 4;
    float muv[8], rsv[8];
#pragma unroll
    for (int i = 0; i < 8; ++i) {
        int r = (t + i * 256) >> 5;
        muv[i] = ws[WS_MU + r0 + r];
        rsv[i] = ws[WS_RSTD + r0 + r];
    }
    float acc[4][4] = {};
    for (int c0 = 0; c0 < DIM; c0 += 32) {
#pragma unroll
        for (int i = 0; i < 8; ++i) {
            int idx = t + i * 256;
            int r = idx >> 5, c = idx & 31;
            float raw = emb[(r0 + r) * DIM + c0 + c];
            float v = (raw - muv[i]) * rsv[i] * lnsc[c0 + c] + lnbi[c0 + c];
            As[c * 65 + r] = v;
            Bs[c * 65 + r] = W[(d0 + r) * DIM + c0 + c];
        }
        __syncthreads();
#pragma unroll
        for (int c = 0; c < 32; ++c) {
            float a[4], b[4];
#pragma unroll
            for (int i = 0; i < 4; ++i) a[i] = As[c * 65 + ty * 4 + i];
#pragma unroll
            for (int j = 0; j < 4; ++j) b[j] = Bs[c * 65 + tx * 4 + j];
#pragma unroll
            for (int i = 0; i < 4; ++i)
#pragma unroll
                for (int j = 0; j < 4; ++j) acc[i][j] += a[i] * b[j];
        }
        __syncthreads();
    }
#pragma unroll
    for (int i = 0; i < 4; ++i) {
        int row = r0 + ty * 4 + i, col = d0 + tx * 4;
        float4 v = { acc[i][0] + bias[col], acc[i][1] + bias[col + 1],
                     acc[i][2] + bias[col + 2], acc[i][3] + bias[col + 3] };
        *reinterpret_cast<float4*>(o + row * DIM + col) = v;
        short4 s4 = { f2bf(v.x), f2bf(v.y), f2bf(v.z), f2bf(v.w) };
        int hh = col >> 6, cc = col & 63;
        *reinterpret_cast<short4*>(bfo + ((size_t)(hh * 512) + row) * 64 + cc) = s4;
    }
}

// Fused: q/k f32 [b,n,h,c] -> bf16 [b,h,n,c]  AND  c0/c511 dot tables.
// z=0: X=q, T=rk(f32) -> qbf, C0Q/C511Q.  z=1: X=k, T=rq -> kbf, C0K/C511K.
__global__ __launch_bounds__(256) void qkprep(const float* __restrict__ q,
        const float* __restrict__ k, const float* __restrict__ out_ro,
        float* __restrict__ ws, short* __restrict__ qbf, short* __restrict__ kbf) {
    int z = blockIdx.z;
    int bh = blockIdx.y; int b = bh >> 4, h = bh & 15;
    int row = blockIdx.x * 64 + (threadIdx.x >> 2);
    int seg = (threadIdx.x & 3) * 16;
    const float* X = z ? k : q;
    const float* T = out_ro + (z ? OUT_RQ : OUT_RK);
    short* dst = z ? kbf : qbf;
    const float4* xp = reinterpret_cast<const float4*>(X + (size_t)((b * S + row) * H + h) * DH + seg);
    const float4* t0 = reinterpret_cast<const float4*>(T + h * DH + seg);
    const float4* t1 = reinterpret_cast<const float4*>(T + 511 * DIM + h * DH + seg);
    float d0 = 0.f, d1 = 0.f;
    short* dbase = dst + ((size_t)bh * 2048 + row) * 64 + seg;
#pragma unroll
    for (int i = 0; i < 4; ++i) {
        float4 x = xp[i], a = t0[i], c = t1[i];
        d0 += x.x * a.x + x.y * a.y + x.z * a.z + x.w * a.w;
        d1 += x.x * c.x + x.y * c.y + x.z * c.z + x.w * c.w;
        short4 o = { f2bf(x.x), f2bf(x.y), f2bf(x.z), f2bf(x.w) };
        *reinterpret_cast<short4*>(dbase + i * 4) = o;
    }
    d0 += __shfl_xor(d0, 1); d0 += __shfl_xor(d0, 2);
    d1 += __shfl_xor(d1, 1); d1 += __shfl_xor(d1, 2);
    if ((threadIdx.x & 3) == 0) {
        int o = bh * S + row;
        if (!z) { ws[WS_C0Q + o] = d0; ws[WS_C511Q + o] = d1; }
        else    { ws[WS_C0K + o] = d0; ws[WS_C511K + o] = d1; }
    }
}

// Unified output kernel over all 64x64 tiles of both sides.
// blockIdx.x = nt*32+jt, blockIdx.y = bh, blockIdx.z = PK (0: QP from q&rk, 1: PK from k&rq)
__global__ __launch_bounds__(256) void outk(const short* __restrict__ qbf,
        const short* __restrict__ kbf, const short* __restrict__ rqbf,
        const short* __restrict__ rkbf, const float* __restrict__ ws,
        float* __restrict__ out) {
    __shared__ short Xs[64 * 72];
    __shared__ short Ts[128 * 72];
    __shared__ float Yt[64 * 132];

    int PK = blockIdx.z;
    int bh = blockIdx.y; int h = bh & 15;
    int nt = blockIdx.x >> 5, jt = blockIdx.x & 31;
    int n0 = nt * 64, j0 = jt * 64;
    int jlo = nt > 8 ? nt - 8 : 0;
    int t = threadIdx.x;
    float* obase = out + (PK ? OUT_PK : OUT_QP) + (size_t)bh * S * S;

    if (jt < jlo || jt > nt) {
        // Flat tile: rel=0 (left) or rel=511 (right)
        int left = jt < jlo;
        const float* cv = ws + (PK ? (left ? WS_C0K : WS_C511K)
                                   : (left ? WS_C0Q : WS_C511Q)) + bh * S;
        int col4 = t & 15, r0w = t >> 4;
        if (PK) {
            float4 v = *reinterpret_cast<const float4*>(cv + j0 + col4 * 4);
#pragma unroll
            for (int i = 0; i < 4; ++i) {
                int n = n0 + r0w + i * 16;
                *reinterpret_cast<float4*>(obase + (size_t)n * S + j0 + col4 * 4) = v;
            }
        } else {
#pragma unroll
            for (int i = 0; i < 4; ++i) {
                int n = n0 + r0w + i * 16;
                float vs = cv[n];
                float4 v = { vs, vs, vs, vs };
                *reinterpret_cast<float4*>(obase + (size_t)n * S + j0 + col4 * 4) = v;
            }
        }
        return;
    }

    // Band tile
    int rlo = 511 + j0 - (n0 + 63); rlo = rlo < 0 ? 0 : rlo;
    int rhi = 511 + (j0 + 63) - n0; rhi = rhi > 511 ? 511 : rhi;
    int nT = rhi - rlo + 1;   // <= 127

    const short* xb = (PK ? kbf : qbf) + ((size_t)bh * 2048 + (PK ? j0 : n0)) * 64;
    const short* tb = (PK ? rqbf : rkbf) + ((size_t)h * 512 + rlo) * 64;
#pragma unroll
    for (int i = 0; i < 2; ++i) {
        int idx = t + i * 256, row = idx >> 3, sg = idx & 7;
        *reinterpret_cast<uint4*>(&Xs[row * 72 + sg * 8]) =
            *reinterpret_cast<const uint4*>(xb + row * 64 + sg * 8);
    }
#pragma unroll
    for (int i = 0; i < 4; ++i) {
        int idx = t + i * 256, row = idx >> 3, sg = idx & 7;
        if (row < nT)
            *reinterpret_cast<uint4*>(&Ts[row * 72 + sg * 8]) =
                *reinterpret_cast<const uint4*>(tb + row * 64 + sg * 8);
    }
    __syncthreads();

    int lane = t & 63, w = t >> 6, lr = lane & 15, lg = lane >> 4;
    // Same lane->(row,k-chunk) convention for A and B (k-permutation cancels).
    bf16x8 a0 = *reinterpret_cast<const bf16x8*>(&Xs[(w * 16 + lr) * 72 + lg * 8]);
    bf16x8 a1 = *reinterpret_cast<const bf16x8*>(&Xs[(w * 16 + lr) * 72 + 32 + lg * 8]);
#pragma unroll
    for (int s = 0; s < 8; ++s) {
        bf16x8 b0 = *reinterpret_cast<const bf16x8*>(&Ts[(s * 16 + lr) * 72 + lg * 8]);
        bf16x8 b1 = *reinterpret_cast<const bf16x8*>(&Ts[(s * 16 + lr) * 72 + 32 + lg * 8]);
        f32x4 acc = {0.f, 0.f, 0.f, 0.f};
        acc = __builtin_amdgcn_mfma_f32_16x16x32_bf16(a0, b0, acc, 0, 0, 0);
        acc = __builtin_amdgcn_mfma_f32_16x16x32_bf16(a1, b1, acc, 0, 0, 0);
        // D: col(g)=lane&15 -> Ts row s*16+lr; row(m)=lg*4+reg -> Xs row w*16+lg*4+reg
#pragma unroll
        for (int reg = 0; reg < 4; ++reg)
            Yt[(w * 16 + lg * 4 + reg) * 132 + s * 16 + lr] = acc[reg];
    }
    __syncthreads();

    int tx = t & 15, ty = t >> 4;
#pragma unroll
    for (int i = 0; i < 4; ++i) {
        int rowi = ty + i * 16;
        int n = n0 + rowi;
        float vv[4];
#pragma unroll
        for (int jj = 0; jj < 4; ++jj) {
            int j = j0 + tx * 4 + jj;
            int rel = 511 + j - n;
            rel = rel < 0 ? 0 : (rel > 511 ? 511 : rel);
            int g = rel - rlo;
            int m = PK ? (tx * 4 + jj) : rowi;
            vv[jj] = Yt[m * 132 + g];
        }
        float4 v = { vv[0], vv[1], vv[2], vv[3] };
        *reinterpret_cast<float4*>(obase + (size_t)n * S + j0 + tx * 4) = v;
    }
}

extern "C" void kernel_launch(void* const* d_in, const int* in_sizes, int n_in,
                              void* d_out, int out_size, void* d_ws, size_t ws_size,
                              hipStream_t stream) {
    const float* q    = (const float*)d_in[0];
    const float* k    = (const float*)d_in[1];
    const float* emb  = (const float*)d_in[2];
    const float* lnsc = (const float*)d_in[3];
    const float* lnbi = (const float*)d_in[4];
    const float* Wq   = (const float*)d_in[5];
    const float* bq   = (const float*)d_in[6];
    const float* Wk   = (const float*)d_in[7];
    const float* bk   = (const float*)d_in[8];
    float* out = (float*)d_out;
    float* ws  = (float*)d_ws;

    short* qbf  = (short*)(ws + WS_BF_BASE);
    short* kbf  = qbf + (size_t)4194304;
    short* rqbf = kbf + (size_t)4194304;
    short* rkbf = rqbf + (size_t)524288;

    ln_stats<<<dim3(512), dim3(64), 0, stream>>>(emb, ws);
    proj<<<dim3(8, 16, 2), dim3(256), 0, stream>>>(emb, ws, lnsc, lnbi, Wq, bq, Wk, bk, out, rqbf, rkbf);
    qkprep<<<dim3(32, 32, 2), dim3(256), 0, stream>>>(q, k, out, ws, qbf, kbf);
    outk<<<dim3(1024, 32, 2), dim3(256), 0, stream>>>(qbf, kbf, rqbf, rkbf, ws, out);
}

// Round 4
// 328.254 us; speedup vs baseline: 2.2137x; 1.2498x over previous
//
#include <hip/hip_runtime.h>

#define BB 2
#define S 2048
#define H 16
#define DH 64
#define DIM 1024
#define WIN 512

#define OUT_PK 0
#define OUT_QP 134217728
#define OUT_RQ 268435456
#define OUT_RK 268959744

// ws float offsets
#define WS_MU    0
#define WS_RSTD  512
#define WS_C0Q   1024
#define WS_C511Q (1024 + 65536)
#define WS_C0K   (1024 + 2*65536)
#define WS_C511K (1024 + 3*65536)
#define WS_BF_BASE 263168          // float index where bf16 region starts

typedef short bf16x8 __attribute__((ext_vector_type(8)));
typedef float f32x4 __attribute__((ext_vector_type(4)));

__device__ inline short f2bf(float f) {
    union { float f; unsigned int u; } cv; cv.f = f;
    unsigned int u = cv.u + 0x7FFFu + ((cv.u >> 16) & 1u);
    return (short)(u >> 16);
}

__device__ inline float bf2f(short s) {
    union { unsigned int u; float f; } cv;
    cv.u = ((unsigned int)(unsigned short)s) << 16;
    return cv.f;
}

__global__ void ln_stats(const float* __restrict__ emb, float* __restrict__ ws) {
    int row = blockIdx.x;
    int t = threadIdx.x; // 64 threads
    const float4* rp = reinterpret_cast<const float4*>(emb + row * DIM);
    float s = 0.f, sq = 0.f;
#pragma unroll
    for (int i = 0; i < 4; ++i) {
        float4 v = rp[t + 64 * i];
        s  += v.x + v.y + v.z + v.w;
        sq += v.x * v.x + v.y * v.y + v.z * v.z + v.w * v.w;
    }
    for (int m = 32; m; m >>= 1) { s += __shfl_xor(s, m); sq += __shfl_xor(sq, m); }
    if (t == 0) {
        float mu = s / DIM;
        float var = sq / DIM - mu * mu;
        ws[WS_MU + row] = mu;
        ws[WS_RSTD + row] = rsqrtf(var + 1e-5f);
    }
}

// C[r,d] = sum_c LN(emb)[r,c] * W[d,c] + bias[d];  z=0 -> Wq -> OUT_RQ (+rqbf), z=1 -> Wk -> OUT_RK (+rkbf)
__global__ __launch_bounds__(256) void proj(const float* __restrict__ emb,
        const float* __restrict__ ws, const float* __restrict__ lnsc, const float* __restrict__ lnbi,
        const float* __restrict__ Wq, const float* __restrict__ bq,
        const float* __restrict__ Wk, const float* __restrict__ bk,
        float* __restrict__ out, short* __restrict__ rqbf, short* __restrict__ rkbf) {
    const float* W    = blockIdx.z ? Wk : Wq;
    const float* bias = blockIdx.z ? bk : bq;
    float* o = out + (blockIdx.z ? OUT_RK : OUT_RQ);
    short* bfo = blockIdx.z ? rkbf : rqbf;
    int r0 = blockIdx.x * 64;   // gridDim.x = 8
    int d0 = blockIdx.y * 64;   // gridDim.y = 16
    __shared__ float As[32 * 65];
    __shared__ float Bs[32 * 65];
    int t = threadIdx.x;
    int tx = t & 15, ty = t >> 4;
    float muv[8], rsv[8];
#pragma unroll
    for (int i = 0; i < 8; ++i) {
        int r = (t + i * 256) >> 5;
        muv[i] = ws[WS_MU + r0 + r];
        rsv[i] = ws[WS_RSTD + r0 + r];
    }
    float acc[4][4] = {};
    for (int c0 = 0; c0 < DIM; c0 += 32) {
#pragma unroll
        for (int i = 0; i < 8; ++i) {
            int idx = t + i * 256;
            int r = idx >> 5, c = idx & 31;
            float raw = emb[(r0 + r) * DIM + c0 + c];
            float v = (raw - muv[i]) * rsv[i] * lnsc[c0 + c] + lnbi[c0 + c];
            As[c * 65 + r] = v;
            Bs[c * 65 + r] = W[(d0 + r) * DIM + c0 + c];
        }
        __syncthreads();
#pragma unroll
        for (int c = 0; c < 32; ++c) {
            float a[4], b[4];
#pragma unroll
            for (int i = 0; i < 4; ++i) a[i] = As[c * 65 + ty * 4 + i];
#pragma unroll
            for (int j = 0; j < 4; ++j) b[j] = Bs[c * 65 + tx * 4 + j];
#pragma unroll
            for (int i = 0; i < 4; ++i)
#pragma unroll
                for (int j = 0; j < 4; ++j) acc[i][j] += a[i] * b[j];
        }
        __syncthreads();
    }
#pragma unroll
    for (int i = 0; i < 4; ++i) {
        int row = r0 + ty * 4 + i, col = d0 + tx * 4;
        float4 v = { acc[i][0] + bias[col], acc[i][1] + bias[col + 1],
                     acc[i][2] + bias[col + 2], acc[i][3] + bias[col + 3] };
        *reinterpret_cast<float4*>(o + row * DIM + col) = v;
        short4 s4 = { f2bf(v.x), f2bf(v.y), f2bf(v.z), f2bf(v.w) };
        int hh = col >> 6, cc = col & 63;
        *reinterpret_cast<short4*>(bfo + ((size_t)(hh * 512) + row) * 64 + cc) = s4;
    }
}

// Fused: q/k f32 [b,n,h,c] -> bf16 [b,h,n,c]  AND  c0/c511 dot tables.
__global__ __launch_bounds__(256) void qkprep(const float* __restrict__ q,
        const float* __restrict__ k, const float* __restrict__ out_ro,
        float* __restrict__ ws, short* __restrict__ qbf, short* __restrict__ kbf) {
    int z = blockIdx.z;
    int bh = blockIdx.y; int b = bh >> 4, h = bh & 15;
    int row = blockIdx.x * 64 + (threadIdx.x >> 2);
    int seg = (threadIdx.x & 3) * 16;
    const float* X = z ? k : q;
    const float* T = out_ro + (z ? OUT_RQ : OUT_RK);
    short* dst = z ? kbf : qbf;
    const float4* xp = reinterpret_cast<const float4*>(X + (size_t)((b * S + row) * H + h) * DH + seg);
    const float4* t0 = reinterpret_cast<const float4*>(T + h * DH + seg);
    const float4* t1 = reinterpret_cast<const float4*>(T + 511 * DIM + h * DH + seg);
    float d0 = 0.f, d1 = 0.f;
    short* dbase = dst + ((size_t)bh * 2048 + row) * 64 + seg;
#pragma unroll
    for (int i = 0; i < 4; ++i) {
        float4 x = xp[i], a = t0[i], c = t1[i];
        d0 += x.x * a.x + x.y * a.y + x.z * a.z + x.w * a.w;
        d1 += x.x * c.x + x.y * c.y + x.z * c.z + x.w * c.w;
        short4 o = { f2bf(x.x), f2bf(x.y), f2bf(x.z), f2bf(x.w) };
        *reinterpret_cast<short4*>(dbase + i * 4) = o;
    }
    d0 += __shfl_xor(d0, 1); d0 += __shfl_xor(d0, 2);
    d1 += __shfl_xor(d1, 1); d1 += __shfl_xor(d1, 2);
    if ((threadIdx.x & 3) == 0) {
        int o = bh * S + row;
        if (!z) { ws[WS_C0Q + o] = d0; ws[WS_C511Q + o] = d1; }
        else    { ws[WS_C0K + o] = d0; ws[WS_C511K + o] = d1; }
    }
}

// Unified output kernel over all 64x64 tiles of both sides.
// blockIdx.x = nt*32+jt, blockIdx.y = bh, blockIdx.z = PK
// LDS = Yt only (bf16, 16.9 KB) -> 8 blocks/CU; fragments come straight from L2.
__global__ __launch_bounds__(256) void outk(const short* __restrict__ qbf,
        const short* __restrict__ kbf, const short* __restrict__ rqbf,
        const short* __restrict__ rkbf, const float* __restrict__ ws,
        float* __restrict__ out) {
    __shared__ short Yt[64 * 132];

    int PK = blockIdx.z;
    int bh = blockIdx.y; int h = bh & 15;
    int nt = blockIdx.x >> 5, jt = blockIdx.x & 31;
    int n0 = nt * 64, j0 = jt * 64;
    int jlo = nt > 8 ? nt - 8 : 0;
    int t = threadIdx.x;
    float* obase = out + (PK ? OUT_PK : OUT_QP) + (size_t)bh * S * S;

    if (jt < jlo || jt > nt) {
        // Flat tile: rel=0 (left) or rel=511 (right)
        int left = jt < jlo;
        const float* cv = ws + (PK ? (left ? WS_C0K : WS_C511K)
                                   : (left ? WS_C0Q : WS_C511Q)) + bh * S;
        int col4 = t & 15, r0w = t >> 4;
        if (PK) {
            float4 v = *reinterpret_cast<const float4*>(cv + j0 + col4 * 4);
#pragma unroll
            for (int i = 0; i < 4; ++i) {
                int n = n0 + r0w + i * 16;
                *reinterpret_cast<float4*>(obase + (size_t)n * S + j0 + col4 * 4) = v;
            }
        } else {
#pragma unroll
            for (int i = 0; i < 4; ++i) {
                int n = n0 + r0w + i * 16;
                float vs = cv[n];
                float4 v = { vs, vs, vs, vs };
                *reinterpret_cast<float4*>(obase + (size_t)n * S + j0 + col4 * 4) = v;
            }
        }
        return;
    }

    // Band tile
    int rlo = 511 + j0 - (n0 + 63); rlo = rlo < 0 ? 0 : rlo;
    int rhi = 511 + (j0 + 63) - n0; rhi = rhi > 511 ? 511 : rhi;

    const short* xb = (PK ? kbf : qbf) + ((size_t)bh * 2048 + (PK ? j0 : n0)) * 64;
    const short* tbase = (PK ? rqbf : rkbf) + (size_t)h * 512 * 64;

    int lane = t & 63, w = t >> 6, lr = lane & 15, lg = lane >> 4;
    // A fragments from global: rows w*16+lr, chunks lg*8 / 32+lg*8.
    // Same (lr, lg) convention for A and B => HW k-permutation cancels (verified R2/R3).
    const short* arow = xb + (w * 16 + lr) * 64 + lg * 8;
    bf16x8 a0 = *reinterpret_cast<const bf16x8*>(arow);
    bf16x8 a1 = *reinterpret_cast<const bf16x8*>(arow + 32);
#pragma unroll
    for (int s = 0; s < 8; ++s) {
        int trow = rlo + s * 16 + lr;
        trow = trow > 511 ? 511 : trow;   // stay in-bounds; g>=nT never gathered
        const short* brow = tbase + trow * 64 + lg * 8;
        bf16x8 b0 = *reinterpret_cast<const bf16x8*>(brow);
        bf16x8 b1 = *reinterpret_cast<const bf16x8*>(brow + 32);
        f32x4 acc = {0.f, 0.f, 0.f, 0.f};
        acc = __builtin_amdgcn_mfma_f32_16x16x32_bf16(a0, b0, acc, 0, 0, 0);
        acc = __builtin_amdgcn_mfma_f32_16x16x32_bf16(a1, b1, acc, 0, 0, 0);
        // D: col(g)=lr -> T row s*16+lr; row(m)=lg*4+reg
#pragma unroll
        for (int reg = 0; reg < 4; ++reg)
            Yt[(w * 16 + lg * 4 + reg) * 132 + s * 16 + lr] = f2bf(acc[reg]);
    }
    __syncthreads();

    int tx = t & 15, ty = t >> 4;
#pragma unroll
    for (int i = 0; i < 4; ++i) {
        int rowi = ty + i * 16;
        int n = n0 + rowi;
        float vv[4];
#pragma unroll
        for (int jj = 0; jj < 4; ++jj) {
            int j = j0 + tx * 4 + jj;
            int rel = 511 + j - n;
            rel = rel < 0 ? 0 : (rel > 511 ? 511 : rel);
            int g = rel - rlo;
            int m = PK ? (tx * 4 + jj) : rowi;
            vv[jj] = bf2f(Yt[m * 132 + g]);
        }
        float4 v = { vv[0], vv[1], vv[2], vv[3] };
        *reinterpret_cast<float4*>(obase + (size_t)n * S + j0 + tx * 4) = v;
    }
}

extern "C" void kernel_launch(void* const* d_in, const int* in_sizes, int n_in,
                              void* d_out, int out_size, void* d_ws, size_t ws_size,
                              hipStream_t stream) {
    const float* q    = (const float*)d_in[0];
    const float* k    = (const float*)d_in[1];
    const float* emb  = (const float*)d_in[2];
    const float* lnsc = (const float*)d_in[3];
    const float* lnbi = (const float*)d_in[4];
    const float* Wq   = (const float*)d_in[5];
    const float* bq   = (const float*)d_in[6];
    const float* Wk   = (const float*)d_in[7];
    const float* bk   = (const float*)d_in[8];
    float* out = (float*)d_out;
    float* ws  = (float*)d_ws;

    short* qbf  = (short*)(ws + WS_BF_BASE);
    short* kbf  = qbf + (size_t)4194304;
    short* rqbf = kbf + (size_t)4194304;
    short* rkbf = rqbf + (size_t)524288;

    ln_stats<<<dim3(512), dim3(64), 0, stream>>>(emb, ws);
    proj<<<dim3(8, 16, 2), dim3(256), 0, stream>>>(emb, ws, lnsc, lnbi, Wq, bq, Wk, bk, out, rqbf, rkbf);
    qkprep<<<dim3(32, 32, 2), dim3(256), 0, stream>>>(q, k, out, ws, qbf, kbf);
    outk<<<dim3(1024, 32, 2), dim3(256), 0, stream>>>(qbf, kbf, rqbf, rkbf, ws, out);
}

// Round 5
// 280.585 us; speedup vs baseline: 2.5898x; 1.1699x over previous
//
#include <hip/hip_runtime.h>

#define BB 2
#define S 2048
#define H 16
#define DH 64
#define DIM 1024
#define WIN 512

#define OUT_PK 0
#define OUT_QP 134217728
#define OUT_RQ 268435456
#define OUT_RK 268959744

// ws float offsets
#define WS_C0Q   1024
#define WS_C511Q (1024 + 65536)
#define WS_C0K   (1024 + 2*65536)
#define WS_C511K (1024 + 3*65536)
#define WS_BF_BASE 263168          // float index where bf16 region starts

typedef short bf16x8 __attribute__((ext_vector_type(8)));
typedef float f32x4 __attribute__((ext_vector_type(4)));

__device__ inline short f2bf(float f) {
    union { float f; unsigned int u; } cv; cv.f = f;
    unsigned int u = cv.u + 0x7FFFu + ((cv.u >> 16) & 1u);
    return (short)(u >> 16);
}

__device__ inline float bf2f(short s) {
    union { unsigned int u; float f; } cv;
    cv.u = ((unsigned int)(unsigned short)s) << 16;
    return cv.f;
}

// Fused LN-stats + C[r,d] = sum_c LN(emb)[r,c] * W[d,c] + bias[d]
// z=0 -> Wq -> OUT_RQ (+rqbf), z=1 -> Wk -> OUT_RK (+rkbf)
__global__ __launch_bounds__(256) void proj(const float* __restrict__ emb,
        const float* __restrict__ lnsc, const float* __restrict__ lnbi,
        const float* __restrict__ Wq, const float* __restrict__ bq,
        const float* __restrict__ Wk, const float* __restrict__ bk,
        float* __restrict__ out, short* __restrict__ rqbf, short* __restrict__ rkbf) {
    const float* W    = blockIdx.z ? Wk : Wq;
    const float* bias = blockIdx.z ? bk : bq;
    float* o = out + (blockIdx.z ? OUT_RK : OUT_RQ);
    short* bfo = blockIdx.z ? rkbf : rqbf;
    int r0 = blockIdx.x * 64;   // gridDim.x = 8
    int d0 = blockIdx.y * 64;   // gridDim.y = 16
    __shared__ float As[32 * 65];
    __shared__ float Bs[32 * 65];
    __shared__ float smu[64];
    __shared__ float srs[64];
    int t = threadIdx.x;
    int tx = t & 15, ty = t >> 4;

    // Phase 0: LN stats for rows r0..r0+63 (4 threads per row)
    {
        int rr = t >> 2, p = t & 3;
        const float4* rp = reinterpret_cast<const float4*>(emb + (r0 + rr) * DIM + p * 256);
        float s = 0.f, sq = 0.f;
#pragma unroll
        for (int i = 0; i < 64; ++i) {
            float4 v = rp[i];
            s  += v.x + v.y + v.z + v.w;
            sq += v.x * v.x + v.y * v.y + v.z * v.z + v.w * v.w;
        }
        s += __shfl_xor(s, 1); sq += __shfl_xor(sq, 1);
        s += __shfl_xor(s, 2); sq += __shfl_xor(sq, 2);
        if (p == 0) {
            float mu = s / DIM;
            float var = sq / DIM - mu * mu;
            smu[rr] = mu;
            srs[rr] = rsqrtf(var + 1e-5f);
        }
    }
    __syncthreads();

    float acc[4][4] = {};
    for (int c0 = 0; c0 < DIM; c0 += 32) {
#pragma unroll
        for (int i = 0; i < 8; ++i) {
            int idx = t + i * 256;
            int r = idx >> 5, c = idx & 31;
            float raw = emb[(r0 + r) * DIM + c0 + c];
            float v = (raw - smu[r]) * srs[r] * lnsc[c0 + c] + lnbi[c0 + c];
            As[c * 65 + r] = v;
            Bs[c * 65 + r] = W[(d0 + r) * DIM + c0 + c];
        }
        __syncthreads();
#pragma unroll
        for (int c = 0; c < 32; ++c) {
            float a[4], b[4];
#pragma unroll
            for (int i = 0; i < 4; ++i) a[i] = As[c * 65 + ty * 4 + i];
#pragma unroll
            for (int j = 0; j < 4; ++j) b[j] = Bs[c * 65 + tx * 4 + j];
#pragma unroll
            for (int i = 0; i < 4; ++i)
#pragma unroll
                for (int j = 0; j < 4; ++j) acc[i][j] += a[i] * b[j];
        }
        __syncthreads();
    }
#pragma unroll
    for (int i = 0; i < 4; ++i) {
        int row = r0 + ty * 4 + i, col = d0 + tx * 4;
        float4 v = { acc[i][0] + bias[col], acc[i][1] + bias[col + 1],
                     acc[i][2] + bias[col + 2], acc[i][3] + bias[col + 3] };
        *reinterpret_cast<float4*>(o + row * DIM + col) = v;
        short4 s4 = { f2bf(v.x), f2bf(v.y), f2bf(v.z), f2bf(v.w) };
        int hh = col >> 6, cc = col & 63;
        *reinterpret_cast<short4*>(bfo + ((size_t)(hh * 512) + row) * 64 + cc) = s4;
    }
}

// Fused: q/k f32 [b,n,h,c] -> bf16 [b,h,n,c]  AND  c0/c511 dot tables.
__global__ __launch_bounds__(256) void qkprep(const float* __restrict__ q,
        const float* __restrict__ k, const float* __restrict__ out_ro,
        float* __restrict__ ws, short* __restrict__ qbf, short* __restrict__ kbf) {
    int z = blockIdx.z;
    int bh = blockIdx.y; int b = bh >> 4, h = bh & 15;
    int row = blockIdx.x * 64 + (threadIdx.x >> 2);
    int seg = (threadIdx.x & 3) * 16;
    const float* X = z ? k : q;
    const float* T = out_ro + (z ? OUT_RQ : OUT_RK);
    short* dst = z ? kbf : qbf;
    const float4* xp = reinterpret_cast<const float4*>(X + (size_t)((b * S + row) * H + h) * DH + seg);
    const float4* t0 = reinterpret_cast<const float4*>(T + h * DH + seg);
    const float4* t1 = reinterpret_cast<const float4*>(T + 511 * DIM + h * DH + seg);
    float d0 = 0.f, d1 = 0.f;
    short* dbase = dst + ((size_t)bh * 2048 + row) * 64 + seg;
#pragma unroll
    for (int i = 0; i < 4; ++i) {
        float4 x = xp[i], a = t0[i], c = t1[i];
        d0 += x.x * a.x + x.y * a.y + x.z * a.z + x.w * a.w;
        d1 += x.x * c.x + x.y * c.y + x.z * c.z + x.w * c.w;
        short4 o = { f2bf(x.x), f2bf(x.y), f2bf(x.z), f2bf(x.w) };
        *reinterpret_cast<short4*>(dbase + i * 4) = o;
    }
    d0 += __shfl_xor(d0, 1); d0 += __shfl_xor(d0, 2);
    d1 += __shfl_xor(d1, 1); d1 += __shfl_xor(d1, 2);
    if ((threadIdx.x & 3) == 0) {
        int o = bh * S + row;
        if (!z) { ws[WS_C0Q + o] = d0; ws[WS_C511Q + o] = d1; }
        else    { ws[WS_C0K + o] = d0; ws[WS_C511K + o] = d1; }
    }
}

// Unified output kernel, 1D grid 65536 with bijective XCD swizzle.
// work id wg = ((PK*32)+bh)*1024 + nt*32 + jt
__global__ __launch_bounds__(256) void outk(const short* __restrict__ qbf,
        const short* __restrict__ kbf, const short* __restrict__ rqbf,
        const short* __restrict__ rkbf, const float* __restrict__ ws,
        float* __restrict__ out) {
    __shared__ short Yt[64 * 132];

    int bid = blockIdx.x;
    int wg = (bid & 7) * 8192 + (bid >> 3);   // 65536 % 8 == 0 -> bijective
    int PK = wg >> 15;
    int bh = (wg >> 10) & 31; int h = bh & 15;
    int nt = (wg >> 5) & 31, jt = wg & 31;
    int n0 = nt * 64, j0 = jt * 64;
    int jlo = nt > 8 ? nt - 8 : 0;
    int t = threadIdx.x;
    float* obase = out + (PK ? OUT_PK : OUT_QP) + (size_t)bh * S * S;

    if (jt < jlo || jt > nt) {
        // Flat tile: rel=0 (left) or rel=511 (right)
        int left = jt < jlo;
        const float* cv = ws + (PK ? (left ? WS_C0K : WS_C511K)
                                   : (left ? WS_C0Q : WS_C511Q)) + bh * S;
        int col4 = t & 15, r0w = t >> 4;
        if (PK) {
            f32x4 v = *reinterpret_cast<const f32x4*>(cv + j0 + col4 * 4);
#pragma unroll
            for (int i = 0; i < 4; ++i) {
                int n = n0 + r0w + i * 16;
                __builtin_nontemporal_store(v,
                    reinterpret_cast<f32x4*>(obase + (size_t)n * S + j0 + col4 * 4));
            }
        } else {
#pragma unroll
            for (int i = 0; i < 4; ++i) {
                int n = n0 + r0w + i * 16;
                float vs = cv[n];
                f32x4 v = { vs, vs, vs, vs };
                __builtin_nontemporal_store(v,
                    reinterpret_cast<f32x4*>(obase + (size_t)n * S + j0 + col4 * 4));
            }
        }
        return;
    }

    // Band tile
    int rlo = 511 + j0 - (n0 + 63); rlo = rlo < 0 ? 0 : rlo;

    const short* xb = (PK ? kbf : qbf) + ((size_t)bh * 2048 + (PK ? j0 : n0)) * 64;
    const short* tbase = (PK ? rqbf : rkbf) + (size_t)h * 512 * 64;

    int lane = t & 63, w = t >> 6, lr = lane & 15, lg = lane >> 4;
    // Same (lr, lg) convention for A and B => HW k-permutation cancels (verified R2-R4).
    const short* arow = xb + (w * 16 + lr) * 64 + lg * 8;
    bf16x8 a0 = *reinterpret_cast<const bf16x8*>(arow);
    bf16x8 a1 = *reinterpret_cast<const bf16x8*>(arow + 32);
#pragma unroll
    for (int s = 0; s < 8; ++s) {
        int trow = rlo + s * 16 + lr;
        trow = trow > 511 ? 511 : trow;   // in-bounds; g>=nT never gathered
        const short* brow = tbase + trow * 64 + lg * 8;
        bf16x8 b0 = *reinterpret_cast<const bf16x8*>(brow);
        bf16x8 b1 = *reinterpret_cast<const bf16x8*>(brow + 32);
        f32x4 acc = {0.f, 0.f, 0.f, 0.f};
        acc = __builtin_amdgcn_mfma_f32_16x16x32_bf16(a0, b0, acc, 0, 0, 0);
        acc = __builtin_amdgcn_mfma_f32_16x16x32_bf16(a1, b1, acc, 0, 0, 0);
        // lane's acc[reg] = Y[m = w*16+lg*4+reg, g = s*16+lr]
#pragma unroll
        for (int reg = 0; reg < 4; ++reg)
            Yt[(w * 16 + lg * 4 + reg) * 132 + s * 16 + lr] = f2bf(acc[reg]);
    }
    __syncthreads();

    int tx = t & 15, ty = t >> 4;
#pragma unroll
    for (int i = 0; i < 4; ++i) {
        int rowi = ty + i * 16;
        int n = n0 + rowi;
        float vv[4];
#pragma unroll
        for (int jj = 0; jj < 4; ++jj) {
            int j = j0 + tx * 4 + jj;
            int rel = 511 + j - n;
            rel = rel < 0 ? 0 : (rel > 511 ? 511 : rel);
            int g = rel - rlo;
            int m = PK ? (tx * 4 + jj) : rowi;
            vv[jj] = bf2f(Yt[m * 132 + g]);
        }
        f32x4 v = { vv[0], vv[1], vv[2], vv[3] };
        __builtin_nontemporal_store(v,
            reinterpret_cast<f32x4*>(obase + (size_t)n * S + j0 + tx * 4));
    }
}

extern "C" void kernel_launch(void* const* d_in, const int* in_sizes, int n_in,
                              void* d_out, int out_size, void* d_ws, size_t ws_size,
                              hipStream_t stream) {
    const float* q    = (const float*)d_in[0];
    const float* k    = (const float*)d_in[1];
    const float* emb  = (const float*)d_in[2];
    const float* lnsc = (const float*)d_in[3];
    const float* lnbi = (const float*)d_in[4];
    const float* Wq   = (const float*)d_in[5];
    const float* bq   = (const float*)d_in[6];
    const float* Wk   = (const float*)d_in[7];
    const float* bk   = (const float*)d_in[8];
    float* out = (float*)d_out;
    float* ws  = (float*)d_ws;

    short* qbf  = (short*)(ws + WS_BF_BASE);
    short* kbf  = qbf + (size_t)4194304;
    short* rqbf = kbf + (size_t)4194304;
    short* rkbf = rqbf + (size_t)524288;

    proj<<<dim3(8, 16, 2), dim3(256), 0, stream>>>(emb, lnsc, lnbi, Wq, bq, Wk, bk, out, rqbf, rkbf);
    qkprep<<<dim3(32, 32, 2), dim3(256), 0, stream>>>(q, k, out, ws, qbf, kbf);
    outk<<<dim3(65536), dim3(256), 0, stream>>>(qbf, kbf, rqbf, rkbf, ws, out);
}

// Round 6
// 234.551 us; speedup vs baseline: 3.0980x; 1.1963x over previous
//
#include <hip/hip_runtime.h>

#define BB 2
#define S 2048
#define H 16
#define DH 64
#define DIM 1024
#define WIN 512

#define OUT_PK 0
#define OUT_QP 134217728
#define OUT_RQ 268435456
#define OUT_RK 268959744

// ws float offsets
#define WS_C0Q   1024
#define WS_C511Q (1024 + 65536)
#define WS_C0K   (1024 + 2*65536)
#define WS_C511K (1024 + 3*65536)
#define WS_BF_BASE 263168          // float index where bf16 region starts

typedef short bf16x8 __attribute__((ext_vector_type(8)));
typedef float f32x4 __attribute__((ext_vector_type(4)));

__device__ inline short f2bf(float f) {
    union { float f; unsigned int u; } cv; cv.f = f;
    unsigned int u = cv.u + 0x7FFFu + ((cv.u >> 16) & 1u);
    return (short)(u >> 16);
}

__device__ inline float bf2f(short s) {
    union { unsigned int u; float f; } cv;
    cv.u = ((unsigned int)(unsigned short)s) << 16;
    return cv.f;
}

// Fused LN-stats + MFMA GEMM: C[r,d] = sum_c LN(emb)[r,c]*W[d,c] + bias[d]
// z=0 -> Wq -> OUT_RQ (+rqbf), z=1 -> Wk -> OUT_RK (+rkbf)
// Same verified MFMA lane convention as outk: A row = w*16+lr (k-chunk lg*8),
// D: col = lr (B row), row = lg*4+reg.
__global__ __launch_bounds__(256) void proj(const float* __restrict__ emb,
        const float* __restrict__ lnsc, const float* __restrict__ lnbi,
        const float* __restrict__ Wq, const float* __restrict__ bq,
        const float* __restrict__ Wk, const float* __restrict__ bk,
        float* __restrict__ out, short* __restrict__ rqbf, short* __restrict__ rkbf) {
    const float* W    = blockIdx.z ? Wk : Wq;
    const float* bias = blockIdx.z ? bk : bq;
    float* o = out + (blockIdx.z ? OUT_RK : OUT_RQ);
    short* bfo = blockIdx.z ? rkbf : rqbf;
    int r0 = blockIdx.x * 64;   // gridDim.x = 8
    int d0 = blockIdx.y * 64;   // gridDim.y = 16
    __shared__ short As[64 * 72];
    __shared__ short Bs[64 * 72];
    __shared__ float smu[64];
    __shared__ float srs[64];
    int t = threadIdx.x;

    // Phase 0: LN stats for rows r0..r0+63 (4 threads per row)
    {
        int rr = t >> 2, p = t & 3;
        const float4* rp = reinterpret_cast<const float4*>(emb + (r0 + rr) * DIM + p * 256);
        float s = 0.f, sq = 0.f;
#pragma unroll
        for (int i = 0; i < 64; ++i) {
            float4 v = rp[i];
            s  += v.x + v.y + v.z + v.w;
            sq += v.x * v.x + v.y * v.y + v.z * v.z + v.w * v.w;
        }
        s += __shfl_xor(s, 1); sq += __shfl_xor(sq, 1);
        s += __shfl_xor(s, 2); sq += __shfl_xor(sq, 2);
        if (p == 0) {
            float mu = s / DIM;
            float var = sq / DIM - mu * mu;
            smu[rr] = mu;
            srs[rr] = rsqrtf(var + 1e-5f);
        }
    }
    __syncthreads();

    int lane = t & 63, w = t >> 6, lr = lane & 15, lg = lane >> 4;
    int srow = t >> 2, seg = (t & 3) * 16;     // staging: row 0..63, 16 cols each
    float mu = smu[srow], rs = srs[srow];

    f32x4 acc[4] = {};
    for (int c0 = 0; c0 < DIM; c0 += 64) {
        const float4* ep = reinterpret_cast<const float4*>(emb + (size_t)(r0 + srow) * DIM + c0 + seg);
        const float4* wp = reinterpret_cast<const float4*>(W + (size_t)(d0 + srow) * DIM + c0 + seg);
        short4* ad = reinterpret_cast<short4*>(&As[srow * 72 + seg]);
        short4* wd = reinterpret_cast<short4*>(&Bs[srow * 72 + seg]);
#pragma unroll
        for (int i = 0; i < 4; ++i) {
            float4 v = ep[i], wv = wp[i];
            int cb = c0 + seg + i * 4;
            float4 sc = *reinterpret_cast<const float4*>(lnsc + cb);
            float4 bi = *reinterpret_cast<const float4*>(lnbi + cb);
            short4 a4 = { f2bf((v.x - mu) * rs * sc.x + bi.x),
                          f2bf((v.y - mu) * rs * sc.y + bi.y),
                          f2bf((v.z - mu) * rs * sc.z + bi.z),
                          f2bf((v.w - mu) * rs * sc.w + bi.w) };
            short4 w4 = { f2bf(wv.x), f2bf(wv.y), f2bf(wv.z), f2bf(wv.w) };
            ad[i] = a4;
            wd[i] = w4;
        }
        __syncthreads();
#pragma unroll
        for (int kk = 0; kk < 2; ++kk) {
            bf16x8 a = *reinterpret_cast<const bf16x8*>(&As[(w * 16 + lr) * 72 + kk * 32 + lg * 8]);
#pragma unroll
            for (int cg = 0; cg < 4; ++cg) {
                bf16x8 b = *reinterpret_cast<const bf16x8*>(&Bs[(cg * 16 + lr) * 72 + kk * 32 + lg * 8]);
                acc[cg] = __builtin_amdgcn_mfma_f32_16x16x32_bf16(a, b, acc[cg], 0, 0, 0);
            }
        }
        __syncthreads();
    }
    // Epilogue: lane holds D[row m = w*16+lg*4+reg][col = d0+cg*16+lr]
#pragma unroll
    for (int cg = 0; cg < 4; ++cg) {
        int col = d0 + cg * 16 + lr;
        float bv = bias[col];
        int hh = col >> 6, cc = col & 63;
#pragma unroll
        for (int reg = 0; reg < 4; ++reg) {
            int rr = r0 + w * 16 + lg * 4 + reg;
            float val = acc[cg][reg] + bv;
            o[(size_t)rr * DIM + col] = val;
            bfo[((size_t)(hh * 512) + rr) * 64 + cc] = f2bf(val);
        }
    }
}

// Fused: q/k f32 [b,n,h,c] -> bf16 [b,h,n,c]  AND  c0/c511 dot tables.
__global__ __launch_bounds__(256) void qkprep(const float* __restrict__ q,
        const float* __restrict__ k, const float* __restrict__ out_ro,
        float* __restrict__ ws, short* __restrict__ qbf, short* __restrict__ kbf) {
    int z = blockIdx.z;
    int bh = blockIdx.y; int b = bh >> 4, h = bh & 15;
    int row = blockIdx.x * 64 + (threadIdx.x >> 2);
    int seg = (threadIdx.x & 3) * 16;
    const float* X = z ? k : q;
    const float* T = out_ro + (z ? OUT_RQ : OUT_RK);
    short* dst = z ? kbf : qbf;
    const float4* xp = reinterpret_cast<const float4*>(X + (size_t)((b * S + row) * H + h) * DH + seg);
    const float4* t0 = reinterpret_cast<const float4*>(T + h * DH + seg);
    const float4* t1 = reinterpret_cast<const float4*>(T + 511 * DIM + h * DH + seg);
    float d0 = 0.f, d1 = 0.f;
    short* dbase = dst + ((size_t)bh * 2048 + row) * 64 + seg;
#pragma unroll
    for (int i = 0; i < 4; ++i) {
        float4 x = xp[i], a = t0[i], c = t1[i];
        d0 += x.x * a.x + x.y * a.y + x.z * a.z + x.w * a.w;
        d1 += x.x * c.x + x.y * c.y + x.z * c.z + x.w * c.w;
        short4 o = { f2bf(x.x), f2bf(x.y), f2bf(x.z), f2bf(x.w) };
        *reinterpret_cast<short4*>(dbase + i * 4) = o;
    }
    d0 += __shfl_xor(d0, 1); d0 += __shfl_xor(d0, 2);
    d1 += __shfl_xor(d1, 1); d1 += __shfl_xor(d1, 2);
    if ((threadIdx.x & 3) == 0) {
        int o = bh * S + row;
        if (!z) { ws[WS_C0Q + o] = d0; ws[WS_C511Q + o] = d1; }
        else    { ws[WS_C0K + o] = d0; ws[WS_C511K + o] = d1; }
    }
}

// Unified output kernel, 1D grid 65536 with bijective XCD swizzle.
// work id wg = ((PK*32)+bh)*1024 + nt*32 + jt
__global__ __launch_bounds__(256) void outk(const short* __restrict__ qbf,
        const short* __restrict__ kbf, const short* __restrict__ rqbf,
        const short* __restrict__ rkbf, const float* __restrict__ ws,
        float* __restrict__ out) {
    __shared__ short Yt[64 * 132];

    int bid = blockIdx.x;
    int wg = (bid & 7) * 8192 + (bid >> 3);   // 65536 % 8 == 0 -> bijective
    int PK = wg >> 15;
    int bh = (wg >> 10) & 31; int h = bh & 15;
    int nt = (wg >> 5) & 31, jt = wg & 31;
    int n0 = nt * 64, j0 = jt * 64;
    int jlo = nt > 8 ? nt - 8 : 0;
    int t = threadIdx.x;
    float* obase = out + (PK ? OUT_PK : OUT_QP) + (size_t)bh * S * S;

    if (jt < jlo || jt > nt) {
        // Flat tile: rel=0 (left) or rel=511 (right)
        int left = jt < jlo;
        const float* cv = ws + (PK ? (left ? WS_C0K : WS_C511K)
                                   : (left ? WS_C0Q : WS_C511Q)) + bh * S;
        int col4 = t & 15, r0w = t >> 4;
        if (PK) {
            f32x4 v = *reinterpret_cast<const f32x4*>(cv + j0 + col4 * 4);
#pragma unroll
            for (int i = 0; i < 4; ++i) {
                int n = n0 + r0w + i * 16;
                __builtin_nontemporal_store(v,
                    reinterpret_cast<f32x4*>(obase + (size_t)n * S + j0 + col4 * 4));
            }
        } else {
#pragma unroll
            for (int i = 0; i < 4; ++i) {
                int n = n0 + r0w + i * 16;
                float vs = cv[n];
                f32x4 v = { vs, vs, vs, vs };
                __builtin_nontemporal_store(v,
                    reinterpret_cast<f32x4*>(obase + (size_t)n * S + j0 + col4 * 4));
            }
        }
        return;
    }

    // Band tile
    int rlo = 511 + j0 - (n0 + 63); rlo = rlo < 0 ? 0 : rlo;

    const short* xb = (PK ? kbf : qbf) + ((size_t)bh * 2048 + (PK ? j0 : n0)) * 64;
    const short* tbase = (PK ? rqbf : rkbf) + (size_t)h * 512 * 64;

    int lane = t & 63, w = t >> 6, lr = lane & 15, lg = lane >> 4;
    // Same (lr, lg) convention for A and B => HW k-permutation cancels (verified R2-R5).
    const short* arow = xb + (w * 16 + lr) * 64 + lg * 8;
    bf16x8 a0 = *reinterpret_cast<const bf16x8*>(arow);
    bf16x8 a1 = *reinterpret_cast<const bf16x8*>(arow + 32);

    // Front all 16 B-loads so their latency overlaps (static indices -> registers).
    bf16x8 b0s[8], b1s[8];
#pragma unroll
    for (int s = 0; s < 8; ++s) {
        int trow = rlo + s * 16 + lr;
        trow = trow > 511 ? 511 : trow;   // in-bounds; g>=nT never gathered
        const short* brow = tbase + trow * 64 + lg * 8;
        b0s[s] = *reinterpret_cast<const bf16x8*>(brow);
        b1s[s] = *reinterpret_cast<const bf16x8*>(brow + 32);
    }
#pragma unroll
    for (int s = 0; s < 8; ++s) {
        f32x4 acc = {0.f, 0.f, 0.f, 0.f};
        acc = __builtin_amdgcn_mfma_f32_16x16x32_bf16(a0, b0s[s], acc, 0, 0, 0);
        acc = __builtin_amdgcn_mfma_f32_16x16x32_bf16(a1, b1s[s], acc, 0, 0, 0);
        // lane's acc[reg] = Y[m = w*16+lg*4+reg, g = s*16+lr]
#pragma unroll
        for (int reg = 0; reg < 4; ++reg)
            Yt[(w * 16 + lg * 4 + reg) * 132 + s * 16 + lr] = f2bf(acc[reg]);
    }
    __syncthreads();

    int tx = t & 15, ty = t >> 4;
#pragma unroll
    for (int i = 0; i < 4; ++i) {
        int rowi = ty + i * 16;
        int n = n0 + rowi;
        float vv[4];
#pragma unroll
        for (int jj = 0; jj < 4; ++jj) {
            int j = j0 + tx * 4 + jj;
            int rel = 511 + j - n;
            rel = rel < 0 ? 0 : (rel > 511 ? 511 : rel);
            int g = rel - rlo;
            int m = PK ? (tx * 4 + jj) : rowi;
            vv[jj] = bf2f(Yt[m * 132 + g]);
        }
        f32x4 v = { vv[0], vv[1], vv[2], vv[3] };
        __builtin_nontemporal_store(v,
            reinterpret_cast<f32x4*>(obase + (size_t)n * S + j0 + tx * 4));
    }
}

extern "C" void kernel_launch(void* const* d_in, const int* in_sizes, int n_in,
                              void* d_out, int out_size, void* d_ws, size_t ws_size,
                              hipStream_t stream) {
    const float* q    = (const float*)d_in[0];
    const float* k    = (const float*)d_in[1];
    const float* emb  = (const float*)d_in[2];
    const float* lnsc = (const float*)d_in[3];
    const float* lnbi = (const float*)d_in[4];
    const float* Wq   = (const float*)d_in[5];
    const float* bq   = (const float*)d_in[6];
    const float* Wk   = (const float*)d_in[7];
    const float* bk   = (const float*)d_in[8];
    float* out = (float*)d_out;
    float* ws  = (float*)d_ws;

    short* qbf  = (short*)(ws + WS_BF_BASE);
    short* kbf  = qbf + (size_t)4194304;
    short* rqbf = kbf + (size_t)4194304;
    short* rkbf = rqbf + (size_t)524288;

    proj<<<dim3(8, 16, 2), dim3(256), 0, stream>>>(emb, lnsc, lnbi, Wq, bq, Wk, bk, out, rqbf, rkbf);
    qkprep<<<dim3(32, 32, 2), dim3(256), 0, stream>>>(q, k, out, ws, qbf, kbf);
    outk<<<dim3(65536), dim3(256), 0, stream>>>(qbf, kbf, rqbf, rkbf, ws, out);
}